// Round 5
// baseline (602.548 us; speedup 1.0000x reference)
//
#include <hip/hip_runtime.h>
#include <math.h>

#define NE 150000

// type ids: SB=0 PQ=1 PV=2 NB=3
__constant__ int c_stype[15] = {2,0,0,2,3,1,0,1,3,1,2,3,2,1,3};
__constant__ int c_dtype[15] = {0,1,3,1,1,3,2,0,0,2,3,2,2,1,3};
__constant__ int c_slot[15]  = {0,0,0,1,2,1,0,1,2,1,2,2,3,3,3};
__constant__ int c_N[4]      = {4000,30000,15000,12000};
__constant__ int c_xoff[4]   = {0,4000,34000,49000};
__constant__ int c_cnt[4]    = {3,4,4,4};
__constant__ int c_aggoff[4] = {0,24000,264000,384000};
__constant__ int c_outoff[4] = {0,48000,528000,768000};
__constant__ int c_aggrows[4]= {24000,240000,120000,96000};
// bucket id prefix: tiles per type = ceil(N[dtype]/1024)
__constant__ int c_tprefix[16] = {0,4,34,46,76,106,118,133,137,141,156,168,183,198,228,240};

__device__ __forceinline__ float eluf(float x){ return x > 0.0f ? x : expm1f(x); }
__device__ __forceinline__ unsigned encf(float f){ unsigned u=__float_as_uint(f); return (u&0x80000000u)? ~u : (u|0x80000000u); }
__device__ __forceinline__ float decf(unsigned u){ return __uint_as_float((u&0x80000000u)? (u^0x80000000u) : ~u); }
__device__ __forceinline__ float RL(float v, int l){ return __uint_as_float(__builtin_amdgcn_readlane(__float_as_uint(v), l)); }

// ---- build x = concat(x_nt, c_nt) for all 61000 nodes ----
__global__ __launch_bounds__(256) void k_build_x(
    const float* __restrict__ xSB, const float* __restrict__ cSB,
    const float* __restrict__ xPQ, const float* __restrict__ cPQ,
    const float* __restrict__ xPV, const float* __restrict__ cPV,
    const float* __restrict__ xNB, const float* __restrict__ cNB,
    float* __restrict__ xall){
  int n = blockIdx.x*256 + threadIdx.x;
  if (n >= 61000) return;
  const float *xp, *cp; int local;
  if (n < 4000)      { xp=xSB; cp=cSB; local=n; }
  else if (n < 34000){ xp=xPQ; cp=cPQ; local=n-4000; }
  else if (n < 49000){ xp=xPV; cp=cPV; local=n-34000; }
  else               { xp=xNB; cp=cNB; local=n-49000; }
  float4 a = ((const float4*)xp)[local];
  float4 b = ((const float4*)cp)[local];
  ((float4*)xall)[n*2+0] = a;
  ((float4*)xall)[n*2+1] = b;
}

__device__ __forceinline__ float dot128(const float* __restrict__ a, const float* __restrict__ b){
  const float4* a4 = (const float4*)a; const float4* b4 = (const float4*)b;
  float s = 0.f;
  #pragma unroll
  for (int h=0; h<32; h++){
    float4 A=a4[h], B=b4[h];
    s = fmaf(A.x,B.x,s); s = fmaf(A.y,B.y,s); s = fmaf(A.z,B.z,s); s = fmaf(A.w,B.w,s);
  }
  return s;
}
__device__ __forceinline__ void halfsum(const float* __restrict__ a, float& s0, float& s1){
  const float4* a4 = (const float4*)a;
  float x0=0.f, x1=0.f;
  #pragma unroll
  for (int h=0; h<16; h++){ float4 A=a4[h]; x0 += A.x+A.y+A.z+A.w; }
  #pragma unroll
  for (int h=16; h<32; h++){ float4 A=a4[h]; x1 += A.x+A.y+A.z+A.w; }
  s0=x0; s1=x1;
}

// ---- derive per-conv small params (160 floats per conv) ----
__global__ __launch_bounds__(128) void k_params(
    const float* __restrict__ Wq, const float* __restrict__ bq,
    const float* __restrict__ Wk, const float* __restrict__ bk,
    const float* __restrict__ Wv, const float* __restrict__ bv,
    const float* __restrict__ We, const float* __restrict__ be,
    const float* __restrict__ Ws, const float* __restrict__ bs,
    float* __restrict__ par){
  const int c = blockIdx.x, tid = threadIdx.x;
  const float* wq = Wq + (size_t)c*1024;
  const float* wk = Wk + (size_t)c*1024;
  const float* wv = Wv + (size_t)c*1024;
  const float* ws = Ws + (size_t)c*1024;
  const float* we = We + (size_t)c*256;
  const float* vbq = bq + (size_t)c*128;
  const float* vbk = bk + (size_t)c*128;
  const float* vbv = bv + (size_t)c*128;
  const float* vbe = be + (size_t)c*128;
  const float* vbs = bs + (size_t)c*128;
  float* P = par + (size_t)c*160;
  if (tid < 64){
    int fd = tid>>3, fs = tid&7;
    P[tid] = dot128(wq + fd*128, wk + fs*128);
    return;
  }
  const int job = tid - 64, grp = job>>3, f = job&7;
  if (grp==0) P[64+f] = dot128(wq + f*128, vbq==vbq? vbk : vbk); // Wq*bk
  else if (grp==1) P[72+f] = dot128(wk + f*128, vbq);
  else if (grp==2) P[80+f] = dot128(wq + f*128, we);
  else if (grp==3) P[88+f] = dot128(wq + f*128, we+128);
  else if (grp==4) P[96+f] = dot128(wq + f*128, vbe);
  else if (grp==5){ float s0,s1; halfsum(wv + f*128, s0,s1); P[104+f]=s0; P[112+f]=s1; }
  else if (grp==6){ float s0,s1; halfsum(ws + f*128, s0,s1); P[120+f]=s0; P[128+f]=s1; }
  else {
    if (f==0){ P[136] = dot128(vbq, vbk);
               float a,b; halfsum(vbs, a,b); P[148]=a; P[149]=b; }
    else if (f==1) P[137] = dot128(vbq, we);
    else if (f==2) P[138] = dot128(vbq, we+128);
    else if (f==3) P[139] = dot128(vbq, vbe);
    else if (f==4){ float a=0.f,b=0.f; for(int h=0;h<64;h++){a+=we[h]; b+=we[64+h];} P[140]=a; P[141]=b; }
    else if (f==5){ float a=0.f,b=0.f; for(int h=0;h<64;h++){a+=we[128+h]; b+=we[192+h];} P[142]=a; P[143]=b; }
    else if (f==6){ float a,b; halfsum(vbv, a,b); P[144]=a; P[145]=b; }
    else          { float a,b; halfsum(vbe, a,b); P[146]=a; P[147]=b; }
  }
}

#define CHUNK 18750

// ---- bucket count: histogram of dst>>10 per edge type ----
__global__ __launch_bounds__(1024) void k_count(const int* __restrict__ eidx,
                                                int* __restrict__ gcnt){
  const int t = blockIdx.y;
  __shared__ int cnt[32];
  if (threadIdx.x < 32) cnt[threadIdx.x] = 0;
  __syncthreads();
  const int* __restrict__ dstp = eidx + (size_t)(t*2+1)*NE;
  const int e0 = blockIdx.x*CHUNK, e1 = min(NE, e0+CHUNK);
  for (int e=e0+threadIdx.x; e<e1; e+=1024) atomicAdd(&cnt[dstp[e]>>10], 1);
  __syncthreads();
  if (threadIdx.x < 32 && cnt[threadIdx.x] > 0)
    atomicAdd(&gcnt[c_tprefix[t] + threadIdx.x], cnt[threadIdx.x]);
}

// ---- per-type exclusive scan of bucket counts -> offsets + cursors ----
__global__ void k_scan(const int* __restrict__ gcnt, int* __restrict__ gofs,
                       int* __restrict__ gcur){
  const int t = threadIdx.x;
  if (t >= 15) return;
  const int b0 = c_tprefix[t], b1 = c_tprefix[t+1];
  int run = t*NE;
  for (int b=b0; b<b1; b++){ gofs[b]=run; gcur[b]=run; run += gcnt[b]; }
}

// ---- scatter packed payload into dst-tile buckets ----
__global__ __launch_bounds__(1024) void k_scatter(const int* __restrict__ eidx,
    const float* __restrict__ eattr, int* __restrict__ gcur,
    unsigned* __restrict__ pbuf, float2* __restrict__ eabuf){
  const int t = blockIdx.y;
  __shared__ int lcnt[32], lbase[32];
  if (threadIdx.x < 32) lcnt[threadIdx.x] = 0;
  __syncthreads();
  const int* __restrict__ dstp = eidx + (size_t)(t*2+1)*NE;
  const int* __restrict__ srcp = eidx + (size_t)(t*2)*NE;
  const float2* __restrict__ ea2 = (const float2*)eattr + (size_t)t*NE;
  const int e0 = blockIdx.x*CHUNK, e1 = min(NE, e0+CHUNK);
  for (int e=e0+threadIdx.x; e<e1; e+=1024) atomicAdd(&lcnt[dstp[e]>>10], 1);
  __syncthreads();
  if (threadIdx.x < 32){
    int cchk = lcnt[threadIdx.x];
    lbase[threadIdx.x] = cchk > 0 ? atomicAdd(&gcur[c_tprefix[t]+threadIdx.x], cchk) : 0;
  }
  __syncthreads();
  if (threadIdx.x < 32) lcnt[threadIdx.x] = 0;
  __syncthreads();
  for (int e=e0+threadIdx.x; e<e1; e+=1024){
    const int d = dstp[e];
    const int tile = d>>10, dl = d&1023;
    const int pos = lbase[tile] + atomicAdd(&lcnt[tile], 1);
    pbuf[pos]  = ((unsigned)srcp[e]<<10) | (unsigned)dl;
    eabuf[pos] = ea2[e];
  }
}

// ---- conv: one block per (type, dst-tile), walks ONLY its bucket ----
__global__ __launch_bounds__(1024) void k_conv(
    const unsigned* __restrict__ pbuf, const float2* __restrict__ eabuf,
    const int* __restrict__ gofs, const int* __restrict__ gcnt,
    const float* __restrict__ xall, const float* __restrict__ par,
    const float* __restrict__ Wl, const float* __restrict__ bl,
    float* __restrict__ g, unsigned* __restrict__ mm){
  const int b = blockIdx.x;
  int t = 0;
  while (b >= c_tprefix[t+1]) ++t;
  const int tile = b - c_tprefix[t];
  const int dt = c_dtype[t], st = c_stype[t];
  const int N = c_N[dt];
  const int nbase = tile << 10;
  const int tileN = min(1024, N - nbase);
  const int tid = threadIdx.x;

  __shared__ float4 H4[6*1024];
  __shared__ float ACC[6*1024];
  __shared__ float sA[160], sB[160], wlb[192];
  __shared__ float smin[16], smax[16];

  if (tid < 160){ sA[tid] = par[(size_t)t*160 + tid]; sB[tid] = par[(size_t)(15+t)*160 + tid]; }
  else if (tid < 352){ int u = tid-160; wlb[u] = (u<128)? Wl[u] : bl[u-128]; }
  for (int k=tid; k<6144; k+=1024) ACC[k]=0.f;
  __syncthreads();

  if (tid < tileN){
    const int n = nbase + tid;
    const float4* xdp = (const float4*)(xall + (size_t)(c_xoff[dt]+n)*8);
    float4 b0v = xdp[0], b1v = xdp[1];
    float xd[8] = {b0v.x,b0v.y,b0v.z,b0v.w,b1v.x,b1v.y,b1v.z,b1v.w};
    float r2a[8], r2b[8];
    #pragma unroll
    for (int fs=0; fs<8; fs++){
      float a = sA[72+fs], bb = sB[72+fs];
      #pragma unroll
      for (int fd=0; fd<8; fd++){ a = fmaf(xd[fd], sA[fd*8+fs], a); bb = fmaf(xd[fd], sB[fd*8+fs], bb); }
      r2a[fs]=a; r2b[fs]=bb;
    }
    float t0a=sA[137], t1a=sA[138], tba=sA[139], u0a=sA[136];
    float t0b=sB[137], t1b=sB[138], tbb=sB[139], u0b=sB[136];
    #pragma unroll
    for (int f=0;f<8;f++){
      t0a = fmaf(xd[f], sA[80+f], t0a);  t0b = fmaf(xd[f], sB[80+f], t0b);
      t1a = fmaf(xd[f], sA[88+f], t1a);  t1b = fmaf(xd[f], sB[88+f], t1b);
      tba = fmaf(xd[f], sA[96+f], tba);  tbb = fmaf(xd[f], sB[96+f], tbb);
      u0a = fmaf(xd[f], sA[64+f], u0a);  u0b = fmaf(xd[f], sB[64+f], u0b);
    }
    H4[tid]        = make_float4(r2a[0],r2a[1],r2a[2],r2a[3]);
    H4[1024+tid]   = make_float4(r2a[4],r2a[5],r2a[6],r2a[7]);
    H4[2048+tid]   = make_float4(r2b[0],r2b[1],r2b[2],r2b[3]);
    H4[3072+tid]   = make_float4(r2b[4],r2b[5],r2b[6],r2b[7]);
    H4[4096+tid]   = make_float4(t0a,t1a,u0a+tba,0.f);
    H4[5120+tid]   = make_float4(t0b,t1b,u0b+tbb,0.f);
  }
  float vA0[8], vA1[8], vB0[8], vB1[8];
  #pragma unroll
  for (int f=0;f<8;f++){ vA0[f]=sA[104+f]; vA1[f]=sA[112+f]; vB0[f]=sB[104+f]; vB1[f]=sB[112+f]; }
  const float cA0x=sA[140], cA0y=sA[142], cA0c=sA[144]+sA[146];
  const float cA1x=sA[141], cA1y=sA[143], cA1c=sA[145]+sA[147];
  const float cB0x=sB[140], cB0y=sB[142], cB0c=sB[144]+sB[146];
  const float cB1x=sB[141], cB1y=sB[143], cB1c=sB[145]+sB[147];
  __syncthreads();

  const int start = gofs[b], count = gcnt[b];
  const float SCALE = 0.08838834764831845f;
  const int xo = c_xoff[st];

  for (int k=tid; k<count; k+=1024){
    const unsigned pk = pbuf[start+k];
    const float2 ea = eabuf[start+k];
    const int dl = pk & 1023u;
    const int src = pk >> 10;
    const float4* xsp = (const float4*)(xall + (size_t)(xo+src)*8);
    float4 a0v = xsp[0], a1v = xsp[1];
    float xs[8] = {a0v.x,a0v.y,a0v.z,a0v.w,a1v.x,a1v.y,a1v.z,a1v.w};
    float4 p0=H4[dl], p1=H4[1024+dl], p2=H4[2048+dl], p3=H4[3072+dl];
    float4 p4=H4[4096+dl], p5=H4[5120+dl];
    float accA = fmaf(ea.x, p4.x, fmaf(ea.y, p4.y, p4.z));
    float accB = fmaf(ea.x, p5.x, fmaf(ea.y, p5.y, p5.z));
    accA = fmaf(xs[0],p0.x, fmaf(xs[1],p0.y, fmaf(xs[2],p0.z, fmaf(xs[3],p0.w, accA))));
    accA = fmaf(xs[4],p1.x, fmaf(xs[5],p1.y, fmaf(xs[6],p1.z, fmaf(xs[7],p1.w, accA))));
    accB = fmaf(xs[0],p2.x, fmaf(xs[1],p2.y, fmaf(xs[2],p2.z, fmaf(xs[3],p2.w, accB))));
    accB = fmaf(xs[4],p3.x, fmaf(xs[5],p3.y, fmaf(xs[6],p3.z, fmaf(xs[7],p3.w, accB))));
    float v0A = fmaf(ea.x,cA0x, fmaf(ea.y,cA0y, cA0c));
    float v1A = fmaf(ea.x,cA1x, fmaf(ea.y,cA1y, cA1c));
    float v0B = fmaf(ea.x,cB0x, fmaf(ea.y,cB0y, cB0c));
    float v1B = fmaf(ea.x,cB1x, fmaf(ea.y,cB1y, cB1c));
    #pragma unroll
    for (int f=0;f<8;f++){
      v0A = fmaf(xs[f], vA0[f], v0A);
      v1A = fmaf(xs[f], vA1[f], v1A);
      v0B = fmaf(xs[f], vB0[f], v0B);
      v1B = fmaf(xs[f], vB1[f], v1B);
    }
    const float peA = __expf(accA * SCALE);
    const float peB = __expf(accB * SCALE);
    atomicAdd(&ACC[dl],      peA);
    atomicAdd(&ACC[1024+dl], peA*v0A);
    atomicAdd(&ACC[2048+dl], peA*v1A);
    atomicAdd(&ACC[3072+dl], peB);
    atomicAdd(&ACC[4096+dl], peB*v0B);
    atomicAdd(&ACC[5120+dl], peB*v1B);
  }
  __syncthreads();

  float lmin = 3.4e38f, lmax = -3.4e38f;
  if (tid < tileN){
    const int n = nbase + tid;
    const float4* xdp = (const float4*)(xall + (size_t)(c_xoff[dt]+n)*8);
    float4 b0v = xdp[0], b1v = xdp[1];
    float xd[8] = {b0v.x,b0v.y,b0v.z,b0v.w,b1v.x,b1v.y,b1v.z,b1v.w};
    const float denA = ACC[tid],      n0A = ACC[1024+tid], n1A = ACC[2048+tid];
    const float denB = ACC[3072+tid], n0B = ACC[4096+tid], n1B = ACC[5120+tid];
    const float invA = 1.0f/(denA + 1e-16f);
    const float invB = 1.0f/(denB + 1e-16f);
    float s0a = fmaf(n0A, invA, sA[148]), s1a = fmaf(n1A, invA, sA[149]);
    float s0b = fmaf(n0B, invB, sB[148]), s1b = fmaf(n1B, invB, sB[149]);
    #pragma unroll
    for (int f=0;f<8;f++){
      s0a = fmaf(xd[f], sA[120+f], s0a); s1a = fmaf(xd[f], sA[128+f], s1a);
      s0b = fmaf(xd[f], sB[120+f], s0b); s1b = fmaf(xd[f], sB[128+f], s1b);
    }
    const int baseA = c_aggoff[dt] + (0*c_cnt[dt] + c_slot[t])*N + n;
    const int baseB = c_aggoff[dt] + (1*c_cnt[dt] + c_slot[t])*N + n;
    ((float2*)g)[baseA] = make_float2(s0a, s1a);
    ((float2*)g)[baseB] = make_float2(s0b, s1b);
    #pragma unroll
    for (int h=0;h<64;h++){
      float za = fmaf(s0a, wlb[h], fmaf(s1a, wlb[64+h], wlb[128+h]));
      float zb = fmaf(s0b, wlb[h], fmaf(s1b, wlb[64+h], wlb[128+h]));
      lmin = fminf(lmin, fminf(za,zb)); lmax = fmaxf(lmax, fmaxf(za,zb));
    }
  }
  #pragma unroll
  for (int m=32;m>=1;m>>=1){
    lmin = fminf(lmin, __shfl_xor(lmin,m));
    lmax = fmaxf(lmax, __shfl_xor(lmax,m));
  }
  const int wid = tid>>6;
  if ((tid&63)==0){ smin[wid]=lmin; smax[wid]=lmax; }
  __syncthreads();
  if (tid==0){
    float mn = smin[0], mx = smax[0];
    for (int k=1;k<16;k++){ mn = fminf(mn, smin[k]); mx = fmaxf(mx, smax[k]); }
    atomicMin(&mm[0], encf(mn));
    atomicMax(&mm[1], encf(mx));
  }
}

// ---- final: wave handles 32 rows (2-row ILP); Wfc column resident in VGPRs ----
__global__ __launch_bounds__(256) void k_final(
    const float* __restrict__ g, const unsigned* __restrict__ mm,
    const float* __restrict__ Wl, const float* __restrict__ bl,
    const float* __restrict__ Wfc, const float* __restrict__ bfc,
    const float* __restrict__ Wl2, const float* __restrict__ bl2,
    float* __restrict__ out){
  const int bid = blockIdx.x;
  int nt, bo;
  if (bid < 188)       { nt=0; bo=0; }
  else if (bid < 2063) { nt=1; bo=188; }
  else if (bid < 3001) { nt=2; bo=2063; }
  else                 { nt=3; bo=3001; }
  const int w = threadIdx.x>>6, lane = threadIdx.x&63;
  const int R = c_aggrows[nt];
  const int r0 = (bid-bo)*128 + w*32;
  if (r0 >= R) return;  // wave-uniform
  const float wl0 = Wl[lane], wl1 = Wl[64+lane], blv = bl[lane];
  const float bfcv = bfc[nt*64+lane];
  const float wl20 = Wl2[lane], wl21 = Wl2[64+lane], bl2v = bl2[lane];
  float wfcr[64];
  const float* W = Wfc + (size_t)nt*4096;
  #pragma unroll
  for (int h=0;h<64;h++) wfcr[h] = W[h*64 + lane];
  const float zmin = decf(mm[0]), zmax = decf(mm[1]);
  const float rmin = 0.1f*eluf(zmin);
  const float rmax = 0.9f + 0.1f*eluf(zmax);
  const float s2 = 2.0f/(rmax - rmin + 1e-5f);
  const int nrows = min(32, R - r0);
  float gx=0.f, gy=0.f;
  if (lane < nrows){
    const float2 gv = ((const float2*)g)[c_aggoff[nt] + r0 + lane];
    gx = gv.x; gy = gv.y;
  }
  const int half = min(16, nrows);
  for (int r=0; r<half; r++){
    const int rb = r+16;
    const bool hasB = rb < nrows;
    const float g0a=RL(gx,r),  g1a=RL(gy,r);
    const float g0b=RL(gx,rb), g1b=RL(gy,rb);
    const float za = fmaf(g0a, wl0, fmaf(g1a, wl1, blv));
    const float zb = fmaf(g0b, wl0, fmaf(g1b, wl1, blv));
    const float na = fmaf(eluf(za) - rmin, s2, -1.0f);
    const float nb = fmaf(eluf(zb) - rmin, s2, -1.0f);
    float acca = bfcv, accb = bfcv;
    #pragma unroll
    for (int h=0;h<64;h++){
      acca = fmaf(RL(na,h), wfcr[h], acca);
      accb = fmaf(RL(nb,h), wfcr[h], accb);
    }
    float ba = eluf(acca), bb = eluf(accb);
    float sa = ba, sb = bb;
    sa += __shfl_xor(sa,16); sb += __shfl_xor(sb,16);
    sa += __shfl_xor(sa,8);  sb += __shfl_xor(sb,8);
    sa += __shfl_xor(sa,4);  sb += __shfl_xor(sb,4);
    sa += __shfl_xor(sa,2);  sb += __shfl_xor(sb,2);
    sa += __shfl_xor(sa,1);  sb += __shfl_xor(sb,1);
    const float h0a = RL(sa,0), h1a = RL(sa,32);
    const float h0b = RL(sb,0), h1b = RL(sb,32);
    const float fa = eluf(fmaf(h0a, wl20, fmaf(h1a, wl21, bl2v)));
    const float fb = eluf(fmaf(h0b, wl20, fmaf(h1b, wl21, bl2v)));
    const size_t orowA = (size_t)c_outoff[nt] + r0 + r;
    out[orowA*64 + lane] = fa;
    out[(orowA + (size_t)R)*64 + lane] = fa;
    if (hasB){
      const size_t orowB = (size_t)c_outoff[nt] + r0 + rb;
      out[orowB*64 + lane] = fb;
      out[(orowB + (size_t)R)*64 + lane] = fb;
    }
  }
}

extern "C" void kernel_launch(void* const* d_in, const int* in_sizes, int n_in,
                              void* d_out, int out_size, void* d_ws, size_t ws_size,
                              hipStream_t stream) {
  const float* xSB = (const float*)d_in[0];
  const float* cSB = (const float*)d_in[1];
  const float* xPQ = (const float*)d_in[2];
  const float* cPQ = (const float*)d_in[3];
  const float* xPV = (const float*)d_in[4];
  const float* cPV = (const float*)d_in[5];
  const float* xNB = (const float*)d_in[6];
  const float* cNB = (const float*)d_in[7];
  const int*   eidx = (const int*)d_in[8];
  const float* eattr= (const float*)d_in[9];
  const float* Wq = (const float*)d_in[10];
  const float* bq = (const float*)d_in[11];
  const float* Wk = (const float*)d_in[12];
  const float* bk = (const float*)d_in[13];
  const float* Wv = (const float*)d_in[14];
  const float* bv = (const float*)d_in[15];
  const float* We = (const float*)d_in[16];
  const float* be = (const float*)d_in[17];
  const float* Ws = (const float*)d_in[18];
  const float* bs = (const float*)d_in[19];
  const float* Wl = (const float*)d_in[20];
  const float* bl = (const float*)d_in[21];
  const float* Wfc= (const float*)d_in[22];
  const float* bfc= (const float*)d_in[23];
  const float* Wl2= (const float*)d_in[24];
  const float* bl2= (const float*)d_in[25];

  float* ws    = (float*)d_ws;
  float* xall  = ws + 0;               // 488000 f
  float* par   = ws + 488000;          // 4800 f
  float* g     = ws + 492800;          // 960000 f
  unsigned* pbuf = (unsigned*)(ws + 1452800); // 2250000 u32
  float2* eabuf  = (float2*)(ws + 3702800);   // 2250000 float2 (8B aligned)
  int* gcnt = (int*)(ws + 8202800);    // 240
  int* gofs = (int*)(ws + 8203040);    // 240
  int* gcur = (int*)(ws + 8203280);    // 240
  unsigned* mm = (unsigned*)(ws + 8203520); // 2

  hipMemsetAsync(gcnt, 0, 240*sizeof(int), stream);
  hipMemsetAsync(mm,   0xFF, 4, stream);
  hipMemsetAsync(mm+1, 0x00, 4, stream);

  k_build_x<<<(61000+255)/256, 256, 0, stream>>>(xSB,cSB,xPQ,cPQ,xPV,cPV,xNB,cNB, xall);
  k_params<<<30, 128, 0, stream>>>(Wq,bq,Wk,bk,Wv,bv,We,be,Ws,bs, par);
  dim3 gb(8, 15);
  k_count<<<gb, 1024, 0, stream>>>(eidx, gcnt);
  k_scan<<<1, 64, 0, stream>>>(gcnt, gofs, gcur);
  k_scatter<<<gb, 1024, 0, stream>>>(eidx, eattr, gcur, pbuf, eabuf);
  k_conv<<<240, 1024, 0, stream>>>(pbuf, eabuf, gofs, gcnt, xall, par, Wl, bl, g, mm);
  k_final<<<3751, 256, 0, stream>>>(g, mm, Wl, bl, Wfc, bfc, Wl2, bl2, (float*)d_out);
}

// Round 6
// 426.583 us; speedup vs baseline: 1.4125x; 1.4125x over previous
//
#include <hip/hip_runtime.h>
#include <hip/hip_fp16.h>
#include <math.h>

#define NE 150000

// type ids: SB=0 PQ=1 PV=2 NB=3
__constant__ int c_stype[15] = {2,0,0,2,3,1,0,1,3,1,2,3,2,1,3};
__constant__ int c_dtype[15] = {0,1,3,1,1,3,2,0,0,2,3,2,2,1,3};
__constant__ int c_slot[15]  = {0,0,0,1,2,1,0,1,2,1,2,2,3,3,3};
__constant__ int c_N[4]      = {4000,30000,15000,12000};
__constant__ int c_xoff[4]   = {0,4000,34000,49000};
__constant__ int c_cnt[4]    = {3,4,4,4};
__constant__ int c_aggoff[4] = {0,24000,264000,384000};
__constant__ int c_outoff[4] = {0,48000,528000,768000};
__constant__ int c_aggrows[4]= {24000,240000,120000,96000};
// bucket id prefix: tiles per type = ceil(N[dtype]/1024)
__constant__ int c_tprefix[16] = {0,4,34,46,76,106,118,133,137,141,156,168,183,198,228,240};
// per-type row-meta offsets (stride N+1, slack unused)
__constant__ int c_toff2[15] = {0,4001,34002,46003,76004,106005,118006,133007,137008,141009,156010,168011,183012,198013,228014};

__device__ __forceinline__ float eluf(float x){ return x > 0.0f ? x : expm1f(x); }
__device__ __forceinline__ unsigned encf(float f){ unsigned u=__float_as_uint(f); return (u&0x80000000u)? ~u : (u|0x80000000u); }
__device__ __forceinline__ float decf(unsigned u){ return __uint_as_float((u&0x80000000u)? (u^0x80000000u) : ~u); }
__device__ __forceinline__ float RL(float v, int l){ return __uint_as_float(__builtin_amdgcn_readlane(__float_as_uint(v), l)); }

// ---- build x = concat(x_nt, c_nt) for all 61000 nodes ----
__global__ __launch_bounds__(256) void k_build_x(
    const float* __restrict__ xSB, const float* __restrict__ cSB,
    const float* __restrict__ xPQ, const float* __restrict__ cPQ,
    const float* __restrict__ xPV, const float* __restrict__ cPV,
    const float* __restrict__ xNB, const float* __restrict__ cNB,
    float* __restrict__ xall){
  int n = blockIdx.x*256 + threadIdx.x;
  if (n >= 61000) return;
  const float *xp, *cp; int local;
  if (n < 4000)      { xp=xSB; cp=cSB; local=n; }
  else if (n < 34000){ xp=xPQ; cp=cPQ; local=n-4000; }
  else if (n < 49000){ xp=xPV; cp=cPV; local=n-34000; }
  else               { xp=xNB; cp=cNB; local=n-49000; }
  float4 a = ((const float4*)xp)[local];
  float4 b = ((const float4*)cp)[local];
  ((float4*)xall)[n*2+0] = a;
  ((float4*)xall)[n*2+1] = b;
}

__device__ __forceinline__ float dot128(const float* __restrict__ a, const float* __restrict__ b){
  const float4* a4 = (const float4*)a; const float4* b4 = (const float4*)b;
  float s = 0.f;
  #pragma unroll
  for (int h=0; h<32; h++){
    float4 A=a4[h], B=b4[h];
    s = fmaf(A.x,B.x,s); s = fmaf(A.y,B.y,s); s = fmaf(A.z,B.z,s); s = fmaf(A.w,B.w,s);
  }
  return s;
}
__device__ __forceinline__ void halfsum(const float* __restrict__ a, float& s0, float& s1){
  const float4* a4 = (const float4*)a;
  float x0=0.f, x1=0.f;
  #pragma unroll
  for (int h=0; h<16; h++){ float4 A=a4[h]; x0 += A.x+A.y+A.z+A.w; }
  #pragma unroll
  for (int h=16; h<32; h++){ float4 A=a4[h]; x1 += A.x+A.y+A.z+A.w; }
  s0=x0; s1=x1;
}

// ---- derive per-conv small params (160 floats per conv) ----
__global__ __launch_bounds__(128) void k_params(
    const float* __restrict__ Wq, const float* __restrict__ bq,
    const float* __restrict__ Wk, const float* __restrict__ bk,
    const float* __restrict__ Wv, const float* __restrict__ bv,
    const float* __restrict__ We, const float* __restrict__ be,
    const float* __restrict__ Ws, const float* __restrict__ bs,
    float* __restrict__ par){
  const int c = blockIdx.x, tid = threadIdx.x;
  const float* wq = Wq + (size_t)c*1024;
  const float* wk = Wk + (size_t)c*1024;
  const float* wv = Wv + (size_t)c*1024;
  const float* ws = Ws + (size_t)c*1024;
  const float* we = We + (size_t)c*256;
  const float* vbq = bq + (size_t)c*128;
  const float* vbk = bk + (size_t)c*128;
  const float* vbv = bv + (size_t)c*128;
  const float* vbe = be + (size_t)c*128;
  const float* vbs = bs + (size_t)c*128;
  float* P = par + (size_t)c*160;
  if (tid < 64){
    int fd = tid>>3, fs = tid&7;
    P[tid] = dot128(wq + fd*128, wk + fs*128);
    return;
  }
  const int job = tid - 64, grp = job>>3, f = job&7;
  if (grp==0) P[64+f] = dot128(wq + f*128, vbk);
  else if (grp==1) P[72+f] = dot128(wk + f*128, vbq);
  else if (grp==2) P[80+f] = dot128(wq + f*128, we);
  else if (grp==3) P[88+f] = dot128(wq + f*128, we+128);
  else if (grp==4) P[96+f] = dot128(wq + f*128, vbe);
  else if (grp==5){ float s0,s1; halfsum(wv + f*128, s0,s1); P[104+f]=s0; P[112+f]=s1; }
  else if (grp==6){ float s0,s1; halfsum(ws + f*128, s0,s1); P[120+f]=s0; P[128+f]=s1; }
  else {
    if (f==0){ P[136] = dot128(vbq, vbk);
               float a,b; halfsum(vbs, a,b); P[148]=a; P[149]=b; }
    else if (f==1) P[137] = dot128(vbq, we);
    else if (f==2) P[138] = dot128(vbq, we+128);
    else if (f==3) P[139] = dot128(vbq, vbe);
    else if (f==4){ float a=0.f,b=0.f; for(int h=0;h<64;h++){a+=we[h]; b+=we[64+h];} P[140]=a; P[141]=b; }
    else if (f==5){ float a=0.f,b=0.f; for(int h=0;h<64;h++){a+=we[128+h]; b+=we[192+h];} P[142]=a; P[143]=b; }
    else if (f==6){ float a,b; halfsum(vbv, a,b); P[144]=a; P[145]=b; }
    else          { float a,b; halfsum(vbe, a,b); P[146]=a; P[147]=b; }
  }
}

// ---- init per-type cursors ----
__global__ void k_init(int* __restrict__ typecur){
  if (threadIdx.x < 15) typecur[threadIdx.x] = threadIdx.x*NE;
}

// ---- bucket sort: one block per (type, 1024-dst-tile). Two passes over the
// type's edges: (1) LDS histogram of in-tile dls + scan + region reservation,
// (2) scatter {src, f16x2 ea} records into dst-sorted order. Emits per-row
// start (gs2) and length (glen). No big-LDS, 240-way parallel.
__global__ __launch_bounds__(1024) void k_bsort(
    const int* __restrict__ eidx, const float* __restrict__ eattr,
    int* __restrict__ typecur, uint2* __restrict__ erec,
    int* __restrict__ gs2, int* __restrict__ glen){
  const int b = blockIdx.x;
  int t = 0;
  while (b >= c_tprefix[t+1]) ++t;
  const int tile = b - c_tprefix[t];
  const int dt = c_dtype[t];
  const int N = c_N[dt];
  const int nbase = tile << 10;
  const int tileN = min(1024, N - nbase);
  const int tid = threadIdx.x;
  const int lane = tid & 63, wid = tid >> 6;

  __shared__ int cnt[1024];
  __shared__ int wsum[16];
  __shared__ int sbase;

  cnt[tid] = 0;
  __syncthreads();
  const int* __restrict__ dstp = eidx + (size_t)(t*2+1)*NE;
  for (int e=tid; e<NE; e+=1024){
    const int dl = dstp[e] - nbase;
    if ((unsigned)dl < (unsigned)tileN) atomicAdd(&cnt[dl], 1);
  }
  __syncthreads();
  // block-wide exclusive scan of cnt[0..1024)
  const int v = cnt[tid];
  int inc = v;
  #pragma unroll
  for (int off=1; off<64; off<<=1){ int u = __shfl_up(inc, off); if (lane>=off) inc += u; }
  if (lane==63) wsum[wid] = inc;
  __syncthreads();
  if (tid==0){
    int r=0;
    for (int k=0;k<16;k++){ int x=wsum[k]; wsum[k]=r; r+=x; }
    sbase = atomicAdd(&typecur[t], r);
  }
  __syncthreads();
  const int pref = wsum[wid] + inc - v;  // exclusive prefix
  const int base = sbase;
  if (tid < tileN){
    gs2 [c_toff2[t] + nbase + tid] = base + pref;
    glen[c_toff2[t] + nbase + tid] = v;
  }
  cnt[tid] = pref;  // relative cursor
  __syncthreads();

  const int* __restrict__ srcp = eidx + (size_t)(t*2)*NE;
  const float2* __restrict__ ea2 = (const float2*)eattr + (size_t)t*NE;
  for (int e=tid; e<NE; e+=1024){
    const int dl = dstp[e] - nbase;
    if ((unsigned)dl < (unsigned)tileN){
      const int pos = base + atomicAdd(&cnt[dl], 1);
      const float2 ea = ea2[e];
      __half2 h2 = __floats2half2_rn(ea.x, ea.y);
      erec[pos] = make_uint2((unsigned)srcp[e], *(unsigned*)&h2);
    }
  }
}

// ---- gather: per (type,node) walk sorted run ONCE, both layers' convs in
// registers. Zero LDS/atomics in the loop. Fuses softmax, skip, minmax.
__global__ __launch_bounds__(256) void k_gather(
    const int* __restrict__ gs2, const int* __restrict__ glen,
    const uint2* __restrict__ erec,
    const float* __restrict__ xall, const float* __restrict__ par,
    const float* __restrict__ Wl, const float* __restrict__ bl,
    float* __restrict__ g, unsigned* __restrict__ mm){
  const int t = blockIdx.y;
  const int dt = c_dtype[t], st = c_stype[t];
  const int N = c_N[dt];
  if (blockIdx.x*256 >= N) return;
  __shared__ float sA[160], sB[160];
  __shared__ float wlb[192];
  __shared__ float smin[4], smax[4];
  const int tid = threadIdx.x;
  if (tid < 160){ sA[tid] = par[(size_t)t*160 + tid]; sB[tid] = par[(size_t)(15+t)*160 + tid]; }
  if (tid < 192) wlb[tid] = (tid<128)? Wl[tid] : bl[tid-128];
  __syncthreads();
  const int n = blockIdx.x*256 + tid;
  const bool valid = n < N;
  float lmin = 3.4e38f, lmax = -3.4e38f;
  if (valid){
    const float4* xdp = (const float4*)(xall + (size_t)(c_xoff[dt]+n)*8);
    float4 b0v = xdp[0], b1v = xdp[1];
    float xd[8] = {b0v.x,b0v.y,b0v.z,b0v.w,b1v.x,b1v.y,b1v.z,b1v.w};
    // per-node hoists for both convs
    float r2a[8], r2b[8];
    #pragma unroll
    for (int fs=0; fs<8; fs++){
      float a = sA[72+fs], bb = sB[72+fs];
      #pragma unroll
      for (int fd=0; fd<8; fd++){ a = fmaf(xd[fd], sA[fd*8+fs], a); bb = fmaf(xd[fd], sB[fd*8+fs], bb); }
      r2a[fs]=a; r2b[fs]=bb;
    }
    float t0a=sA[137], t1a=sA[138], tba=sA[139], u0a=sA[136];
    float t0b=sB[137], t1b=sB[138], tbb=sB[139], u0b=sB[136];
    #pragma unroll
    for (int f=0;f<8;f++){
      t0a = fmaf(xd[f], sA[80+f], t0a);  t0b = fmaf(xd[f], sB[80+f], t0b);
      t1a = fmaf(xd[f], sA[88+f], t1a);  t1b = fmaf(xd[f], sB[88+f], t1b);
      tba = fmaf(xd[f], sA[96+f], tba);  tbb = fmaf(xd[f], sB[96+f], tbb);
      u0a = fmaf(xd[f], sA[64+f], u0a);  u0b = fmaf(xd[f], sB[64+f], u0b);
    }
    const float accda = u0a + tba, accdb = u0b + tbb;
    const int o = c_toff2[t];
    const int js = gs2[o+n], je = js + glen[o+n];
    float denA=0.f, n0A=0.f, n1A=0.f;
    float denB=0.f, n0B=0.f, n1B=0.f;
    for (int j=js; j<je; j++){
      const uint2 rec = erec[j];
      const int src = (int)rec.x;
      const __half2 h2 = *(const __half2*)&rec.y;
      const float eax = __low2float(h2), eay = __high2float(h2);
      const float4* xsp = (const float4*)(xall + (size_t)(c_xoff[st]+src)*8);
      float4 a0v = xsp[0], a1v = xsp[1];
      float xs[8] = {a0v.x,a0v.y,a0v.z,a0v.w,a1v.x,a1v.y,a1v.z,a1v.w};
      float accA = accda, accB = accdb;
      float v0A = fmaf(eax, sA[140], fmaf(eay, sA[142], sA[144]+sA[146]));
      float v1A = fmaf(eax, sA[141], fmaf(eay, sA[143], sA[145]+sA[147]));
      float v0B = fmaf(eax, sB[140], fmaf(eay, sB[142], sB[144]+sB[146]));
      float v1B = fmaf(eax, sB[141], fmaf(eay, sB[143], sB[145]+sB[147]));
      #pragma unroll
      for (int f=0;f<8;f++){
        accA = fmaf(xs[f], r2a[f], accA);   accB = fmaf(xs[f], r2b[f], accB);
        v0A  = fmaf(xs[f], sA[104+f], v0A); v0B  = fmaf(xs[f], sB[104+f], v0B);
        v1A  = fmaf(xs[f], sA[112+f], v1A); v1B  = fmaf(xs[f], sB[112+f], v1B);
      }
      accA = fmaf(eax, t0a, fmaf(eay, t1a, accA));
      accB = fmaf(eax, t0b, fmaf(eay, t1b, accB));
      const float peA = __expf(accA * 0.08838834764831845f);
      const float peB = __expf(accB * 0.08838834764831845f);
      denA += peA; n0A = fmaf(peA, v0A, n0A); n1A = fmaf(peA, v1A, n1A);
      denB += peB; n0B = fmaf(peB, v0B, n0B); n1B = fmaf(peB, v1B, n1B);
    }
    const float invA = 1.0f/(denA + 1e-16f);
    const float invB = 1.0f/(denB + 1e-16f);
    float s0a = fmaf(n0A, invA, sA[148]), s1a = fmaf(n1A, invA, sA[149]);
    float s0b = fmaf(n0B, invB, sB[148]), s1b = fmaf(n1B, invB, sB[149]);
    #pragma unroll
    for (int f=0;f<8;f++){
      s0a = fmaf(xd[f], sA[120+f], s0a); s1a = fmaf(xd[f], sA[128+f], s1a);
      s0b = fmaf(xd[f], sB[120+f], s0b); s1b = fmaf(xd[f], sB[128+f], s1b);
    }
    const int baseA = c_aggoff[dt] + (0*c_cnt[dt] + c_slot[t])*N + n;
    const int baseB = c_aggoff[dt] + (1*c_cnt[dt] + c_slot[t])*N + n;
    ((float2*)g)[baseA] = make_float2(s0a, s1a);
    ((float2*)g)[baseB] = make_float2(s0b, s1b);
    #pragma unroll
    for (int h=0;h<64;h++){
      float za = fmaf(s0a, wlb[h], fmaf(s1a, wlb[64+h], wlb[128+h]));
      float zb = fmaf(s0b, wlb[h], fmaf(s1b, wlb[64+h], wlb[128+h]));
      lmin = fminf(lmin, fminf(za,zb)); lmax = fmaxf(lmax, fmaxf(za,zb));
    }
  }
  #pragma unroll
  for (int m=32;m>=1;m>>=1){
    lmin = fminf(lmin, __shfl_xor(lmin,m));
    lmax = fmaxf(lmax, __shfl_xor(lmax,m));
  }
  const int wv = tid>>6;
  if ((tid&63)==0){ smin[wv]=lmin; smax[wv]=lmax; }
  __syncthreads();
  if (tid==0){
    float mn = fminf(fminf(smin[0],smin[1]), fminf(smin[2],smin[3]));
    float mx = fmaxf(fmaxf(smax[0],smax[1]), fmaxf(smax[2],smax[3]));
    atomicMin(&mm[0], encf(mn));
    atomicMax(&mm[1], encf(mx));
  }
}

// ---- final: wave handles 32 rows (2-row ILP); Wfc column resident in VGPRs ----
__global__ __launch_bounds__(256) void k_final(
    const float* __restrict__ g, const unsigned* __restrict__ mm,
    const float* __restrict__ Wl, const float* __restrict__ bl,
    const float* __restrict__ Wfc, const float* __restrict__ bfc,
    const float* __restrict__ Wl2, const float* __restrict__ bl2,
    float* __restrict__ out){
  const int bid = blockIdx.x;
  int nt, bo;
  if (bid < 188)       { nt=0; bo=0; }
  else if (bid < 2063) { nt=1; bo=188; }
  else if (bid < 3001) { nt=2; bo=2063; }
  else                 { nt=3; bo=3001; }
  const int w = threadIdx.x>>6, lane = threadIdx.x&63;
  const int R = c_aggrows[nt];
  const int r0 = (bid-bo)*128 + w*32;
  if (r0 >= R) return;  // wave-uniform
  const float wl0 = Wl[lane], wl1 = Wl[64+lane], blv = bl[lane];
  const float bfcv = bfc[nt*64+lane];
  const float wl20 = Wl2[lane], wl21 = Wl2[64+lane], bl2v = bl2[lane];
  float wfcr[64];
  const float* W = Wfc + (size_t)nt*4096;
  #pragma unroll
  for (int h=0;h<64;h++) wfcr[h] = W[h*64 + lane];
  const float zmin = decf(mm[0]), zmax = decf(mm[1]);
  const float rmin = 0.1f*eluf(zmin);
  const float rmax = 0.9f + 0.1f*eluf(zmax);
  const float s2 = 2.0f/(rmax - rmin + 1e-5f);
  const int nrows = min(32, R - r0);
  float gx=0.f, gy=0.f;
  if (lane < nrows){
    const float2 gv = ((const float2*)g)[c_aggoff[nt] + r0 + lane];
    gx = gv.x; gy = gv.y;
  }
  const int half = min(16, nrows);
  for (int r=0; r<half; r++){
    const int rb = r+16;
    const bool hasB = rb < nrows;
    const float g0a=RL(gx,r),  g1a=RL(gy,r);
    const float g0b=RL(gx,rb), g1b=RL(gy,rb);
    const float za = fmaf(g0a, wl0, fmaf(g1a, wl1, blv));
    const float zb = fmaf(g0b, wl0, fmaf(g1b, wl1, blv));
    const float na = fmaf(eluf(za) - rmin, s2, -1.0f);
    const float nb = fmaf(eluf(zb) - rmin, s2, -1.0f);
    float acca = bfcv, accb = bfcv;
    #pragma unroll
    for (int h=0;h<64;h++){
      acca = fmaf(RL(na,h), wfcr[h], acca);
      accb = fmaf(RL(nb,h), wfcr[h], accb);
    }
    float ba = eluf(acca), bb = eluf(accb);
    float sa = ba, sb = bb;
    sa += __shfl_xor(sa,16); sb += __shfl_xor(sb,16);
    sa += __shfl_xor(sa,8);  sb += __shfl_xor(sb,8);
    sa += __shfl_xor(sa,4);  sb += __shfl_xor(sb,4);
    sa += __shfl_xor(sa,2);  sb += __shfl_xor(sb,2);
    sa += __shfl_xor(sa,1);  sb += __shfl_xor(sb,1);
    const float h0a = RL(sa,0), h1a = RL(sa,32);
    const float h0b = RL(sb,0), h1b = RL(sb,32);
    const float fa = eluf(fmaf(h0a, wl20, fmaf(h1a, wl21, bl2v)));
    const float fb = eluf(fmaf(h0b, wl20, fmaf(h1b, wl21, bl2v)));
    const size_t orowA = (size_t)c_outoff[nt] + r0 + r;
    out[orowA*64 + lane] = fa;
    out[(orowA + (size_t)R)*64 + lane] = fa;
    if (hasB){
      const size_t orowB = (size_t)c_outoff[nt] + r0 + rb;
      out[orowB*64 + lane] = fb;
      out[(orowB + (size_t)R)*64 + lane] = fb;
    }
  }
}

extern "C" void kernel_launch(void* const* d_in, const int* in_sizes, int n_in,
                              void* d_out, int out_size, void* d_ws, size_t ws_size,
                              hipStream_t stream) {
  const float* xSB = (const float*)d_in[0];
  const float* cSB = (const float*)d_in[1];
  const float* xPQ = (const float*)d_in[2];
  const float* cPQ = (const float*)d_in[3];
  const float* xPV = (const float*)d_in[4];
  const float* cPV = (const float*)d_in[5];
  const float* xNB = (const float*)d_in[6];
  const float* cNB = (const float*)d_in[7];
  const int*   eidx = (const int*)d_in[8];
  const float* eattr= (const float*)d_in[9];
  const float* Wq = (const float*)d_in[10];
  const float* bq = (const float*)d_in[11];
  const float* Wk = (const float*)d_in[12];
  const float* bk = (const float*)d_in[13];
  const float* Wv = (const float*)d_in[14];
  const float* bv = (const float*)d_in[15];
  const float* We = (const float*)d_in[16];
  const float* be = (const float*)d_in[17];
  const float* Ws = (const float*)d_in[18];
  const float* bs = (const float*)d_in[19];
  const float* Wl = (const float*)d_in[20];
  const float* bl = (const float*)d_in[21];
  const float* Wfc= (const float*)d_in[22];
  const float* bfc= (const float*)d_in[23];
  const float* Wl2= (const float*)d_in[24];
  const float* bl2= (const float*)d_in[25];

  float* ws    = (float*)d_ws;
  float* xall  = ws + 0;                    // 488000 f
  float* par   = ws + 488000;               // 4800 f
  float* g     = ws + 492800;               // 960000 f
  uint2* erec  = (uint2*)(ws + 1452800);    // 2250000 uint2 (8B aligned)
  int* gs2     = (int*)(ws + 5952800);      // 240015 i
  int* glen    = (int*)(ws + 6192815);      // 240015 i
  int* typecur = (int*)(ws + 6432830);      // 15 i
  unsigned* mm = (unsigned*)(ws + 6432845); // 2

  hipMemsetAsync(mm,   0xFF, 4, stream);
  hipMemsetAsync(mm+1, 0x00, 4, stream);

  k_build_x<<<(61000+255)/256, 256, 0, stream>>>(xSB,cSB,xPQ,cPQ,xPV,cPV,xNB,cNB, xall);
  k_params<<<30, 128, 0, stream>>>(Wq,bq,Wk,bk,Wv,bv,We,be,Ws,bs, par);
  k_init<<<1, 64, 0, stream>>>(typecur);
  k_bsort<<<240, 1024, 0, stream>>>(eidx, eattr, typecur, erec, gs2, glen);
  dim3 gg((30000+255)/256, 15);
  k_gather<<<gg, 256, 0, stream>>>(gs2, glen, erec, xall, par, Wl, bl, g, mm);
  k_final<<<3751, 256, 0, stream>>>(g, mm, Wl, bl, Wfc, bfc, Wl2, bl2, (float*)d_out);
}

// Round 7
// 397.939 us; speedup vs baseline: 1.5142x; 1.0720x over previous
//
#include <hip/hip_runtime.h>
#include <hip/hip_fp16.h>
#include <math.h>

#define NE 150000

// type ids: SB=0 PQ=1 PV=2 NB=3
__constant__ int c_stype[15] = {2,0,0,2,3,1,0,1,3,1,2,3,2,1,3};
__constant__ int c_dtype[15] = {0,1,3,1,1,3,2,0,0,2,3,2,2,1,3};
__constant__ int c_slot[15]  = {0,0,0,1,2,1,0,1,2,1,2,2,3,3,3};
__constant__ int c_N[4]      = {4000,30000,15000,12000};
__constant__ int c_xoff[4]   = {0,4000,34000,49000};
__constant__ int c_cnt[4]    = {3,4,4,4};
__constant__ int c_aggoff[4] = {0,24000,264000,384000};
__constant__ int c_outoff[4] = {0,48000,528000,768000};
__constant__ int c_aggrows[4]= {24000,240000,120000,96000};
// bucket id prefix: tiles per type = ceil(N[dtype]/1024)
__constant__ int c_tprefix[16] = {0,4,34,46,76,106,118,133,137,141,156,168,183,198,228,240};
// per-type row-meta offsets (stride N+1, slack unused)
__constant__ int c_toff2[15] = {0,4001,34002,46003,76004,106005,118006,133007,137008,141009,156010,168011,183012,198013,228014};

__device__ __forceinline__ float eluf(float x){ return x > 0.0f ? x : expm1f(x); }
__device__ __forceinline__ unsigned encf(float f){ unsigned u=__float_as_uint(f); return (u&0x80000000u)? ~u : (u|0x80000000u); }
__device__ __forceinline__ float decf(unsigned u){ return __uint_as_float((u&0x80000000u)? (u^0x80000000u) : ~u); }
__device__ __forceinline__ float RL(float v, int l){ return __uint_as_float(__builtin_amdgcn_readlane(__float_as_uint(v), l)); }

// ---- build x = concat(x_nt, c_nt) for all 61000 nodes ----
__global__ __launch_bounds__(256) void k_build_x(
    const float* __restrict__ xSB, const float* __restrict__ cSB,
    const float* __restrict__ xPQ, const float* __restrict__ cPQ,
    const float* __restrict__ xPV, const float* __restrict__ cPV,
    const float* __restrict__ xNB, const float* __restrict__ cNB,
    float* __restrict__ xall){
  int n = blockIdx.x*256 + threadIdx.x;
  if (n >= 61000) return;
  const float *xp, *cp; int local;
  if (n < 4000)      { xp=xSB; cp=cSB; local=n; }
  else if (n < 34000){ xp=xPQ; cp=cPQ; local=n-4000; }
  else if (n < 49000){ xp=xPV; cp=cPV; local=n-34000; }
  else               { xp=xNB; cp=cNB; local=n-49000; }
  float4 a = ((const float4*)xp)[local];
  float4 b = ((const float4*)cp)[local];
  ((float4*)xall)[n*2+0] = a;
  ((float4*)xall)[n*2+1] = b;
}

__device__ __forceinline__ float dot128(const float* __restrict__ a, const float* __restrict__ b){
  const float4* a4 = (const float4*)a; const float4* b4 = (const float4*)b;
  float s = 0.f;
  #pragma unroll
  for (int h=0; h<32; h++){
    float4 A=a4[h], B=b4[h];
    s = fmaf(A.x,B.x,s); s = fmaf(A.y,B.y,s); s = fmaf(A.z,B.z,s); s = fmaf(A.w,B.w,s);
  }
  return s;
}
__device__ __forceinline__ void halfsum(const float* __restrict__ a, float& s0, float& s1){
  const float4* a4 = (const float4*)a;
  float x0=0.f, x1=0.f;
  #pragma unroll
  for (int h=0; h<16; h++){ float4 A=a4[h]; x0 += A.x+A.y+A.z+A.w; }
  #pragma unroll
  for (int h=16; h<32; h++){ float4 A=a4[h]; x1 += A.x+A.y+A.z+A.w; }
  s0=x0; s1=x1;
}

// ---- derive per-conv small params (160 floats per conv) ----
__global__ __launch_bounds__(128) void k_params(
    const float* __restrict__ Wq, const float* __restrict__ bq,
    const float* __restrict__ Wk, const float* __restrict__ bk,
    const float* __restrict__ Wv, const float* __restrict__ bv,
    const float* __restrict__ We, const float* __restrict__ be,
    const float* __restrict__ Ws, const float* __restrict__ bs,
    float* __restrict__ par){
  const int c = blockIdx.x, tid = threadIdx.x;
  const float* wq = Wq + (size_t)c*1024;
  const float* wk = Wk + (size_t)c*1024;
  const float* wv = Wv + (size_t)c*1024;
  const float* ws = Ws + (size_t)c*1024;
  const float* we = We + (size_t)c*256;
  const float* vbq = bq + (size_t)c*128;
  const float* vbk = bk + (size_t)c*128;
  const float* vbv = bv + (size_t)c*128;
  const float* vbe = be + (size_t)c*128;
  const float* vbs = bs + (size_t)c*128;
  float* P = par + (size_t)c*160;
  if (tid < 64){
    int fd = tid>>3, fs = tid&7;
    P[tid] = dot128(wq + fd*128, wk + fs*128);
    return;
  }
  const int job = tid - 64, grp = job>>3, f = job&7;
  if (grp==0) P[64+f] = dot128(wq + f*128, vbk);
  else if (grp==1) P[72+f] = dot128(wk + f*128, vbq);
  else if (grp==2) P[80+f] = dot128(wq + f*128, we);
  else if (grp==3) P[88+f] = dot128(wq + f*128, we+128);
  else if (grp==4) P[96+f] = dot128(wq + f*128, vbe);
  else if (grp==5){ float s0,s1; halfsum(wv + f*128, s0,s1); P[104+f]=s0; P[112+f]=s1; }
  else if (grp==6){ float s0,s1; halfsum(ws + f*128, s0,s1); P[120+f]=s0; P[128+f]=s1; }
  else {
    if (f==0){ P[136] = dot128(vbq, vbk);
               float a,b; halfsum(vbs, a,b); P[148]=a; P[149]=b; }
    else if (f==1) P[137] = dot128(vbq, we);
    else if (f==2) P[138] = dot128(vbq, we+128);
    else if (f==3) P[139] = dot128(vbq, vbe);
    else if (f==4){ float a=0.f,b=0.f; for(int h=0;h<64;h++){a+=we[h]; b+=we[64+h];} P[140]=a; P[141]=b; }
    else if (f==5){ float a=0.f,b=0.f; for(int h=0;h<64;h++){a+=we[128+h]; b+=we[192+h];} P[142]=a; P[143]=b; }
    else if (f==6){ float a,b; halfsum(vbv, a,b); P[144]=a; P[145]=b; }
    else          { float a,b; halfsum(vbe, a,b); P[146]=a; P[147]=b; }
  }
}

#define CHUNK 18750

// ---- stage 1a: per-type histogram of dst>>10 (each edge read once) ----
__global__ __launch_bounds__(1024) void k_count(const int* __restrict__ eidx,
                                                int* __restrict__ gcnt){
  const int t = blockIdx.y;
  __shared__ int cnt[32];
  if (threadIdx.x < 32) cnt[threadIdx.x] = 0;
  __syncthreads();
  const int* __restrict__ dstp = eidx + (size_t)(t*2+1)*NE;
  const int e0 = blockIdx.x*CHUNK, e1 = min(NE, e0+CHUNK);
  for (int e=e0+threadIdx.x; e<e1; e+=1024) atomicAdd(&cnt[dstp[e]>>10], 1);
  __syncthreads();
  if (threadIdx.x < 32 && cnt[threadIdx.x] > 0)
    atomicAdd(&gcnt[c_tprefix[t] + threadIdx.x], cnt[threadIdx.x]);
}

// ---- stage 1b: per-type exclusive scan of bucket counts ----
__global__ void k_scan(const int* __restrict__ gcnt, int* __restrict__ gofs,
                       int* __restrict__ gcur){
  const int t = threadIdx.x;
  if (t >= 15) return;
  const int b0 = c_tprefix[t], b1 = c_tprefix[t+1];
  int run = t*NE;
  for (int b=b0; b<b1; b++){ gofs[b]=run; gcur[b]=run; run += gcnt[b]; }
}

// ---- stage 1c: scatter packed (eid<<10)|dl into tile buckets ----
__global__ __launch_bounds__(1024) void k_scatter(const int* __restrict__ eidx,
    int* __restrict__ gcur, unsigned* __restrict__ ebuf){
  const int t = blockIdx.y;
  __shared__ int lcnt[32], lbase[32];
  if (threadIdx.x < 32) lcnt[threadIdx.x] = 0;
  __syncthreads();
  const int* __restrict__ dstp = eidx + (size_t)(t*2+1)*NE;
  const int e0 = blockIdx.x*CHUNK, e1 = min(NE, e0+CHUNK);
  for (int e=e0+threadIdx.x; e<e1; e+=1024) atomicAdd(&lcnt[dstp[e]>>10], 1);
  __syncthreads();
  if (threadIdx.x < 32){
    int cchk = lcnt[threadIdx.x];
    lbase[threadIdx.x] = cchk > 0 ? atomicAdd(&gcur[c_tprefix[t]+threadIdx.x], cchk) : 0;
  }
  __syncthreads();
  if (threadIdx.x < 32) lcnt[threadIdx.x] = 0;
  __syncthreads();
  for (int e=e0+threadIdx.x; e<e1; e+=1024){
    const int d = dstp[e];
    const int tile = d>>10, dl = d&1023;
    const int pos = lbase[tile] + atomicAdd(&lcnt[tile], 1);
    ebuf[pos] = ((unsigned)e<<10) | (unsigned)dl;
  }
}

// ---- stage 2: per-tile row sort. One block per tile bucket; reads ONLY its
// own bucket (sequential). Pass 1: row histogram + scan -> gs2/glen.
// Pass 2: scatter {src, f16x2 ea} into row-sorted erec. ----
__global__ __launch_bounds__(1024) void k_tsort(
    const unsigned* __restrict__ ebuf, const int* __restrict__ eidx,
    const float* __restrict__ eattr,
    const int* __restrict__ gofs, const int* __restrict__ gcnt,
    uint2* __restrict__ erec, int* __restrict__ gs2, int* __restrict__ glen){
  const int b = blockIdx.x;
  int t = 0;
  while (b >= c_tprefix[t+1]) ++t;
  const int tile = b - c_tprefix[t];
  const int dt = c_dtype[t];
  const int N = c_N[dt];
  const int nbase = tile << 10;
  const int tileN = min(1024, N - nbase);
  const int tid = threadIdx.x;
  const int lane = tid & 63, wid = tid >> 6;

  __shared__ int cnt[1024];
  __shared__ int wsum[16];

  cnt[tid] = 0;
  __syncthreads();
  const int start = gofs[b], count = gcnt[b];
  for (int k=tid; k<count; k+=1024) atomicAdd(&cnt[ebuf[start+k] & 1023u], 1);
  __syncthreads();
  const int v = cnt[tid];
  int inc = v;
  #pragma unroll
  for (int off=1; off<64; off<<=1){ int u = __shfl_up(inc, off); if (lane>=off) inc += u; }
  if (lane==63) wsum[wid] = inc;
  __syncthreads();
  if (tid==0){ int r=0; for (int k=0;k<16;k++){ int x=wsum[k]; wsum[k]=r; r+=x; } }
  __syncthreads();
  const int pref = wsum[wid] + inc - v;  // exclusive prefix within bucket
  if (tid < tileN){
    gs2 [c_toff2[t] + nbase + tid] = start + pref;
    glen[c_toff2[t] + nbase + tid] = v;
  }
  cnt[tid] = pref;
  __syncthreads();

  const int* __restrict__ srcp = eidx + (size_t)(t*2)*NE;
  const float2* __restrict__ ea2 = (const float2*)eattr + (size_t)t*NE;
  for (int k=tid; k<count; k+=1024){
    const unsigned u = ebuf[start+k];
    const int dl = u & 1023u;
    const int eid = u >> 10;
    const int pos = start + atomicAdd(&cnt[dl], 1);
    const float2 ea = ea2[eid];
    __half2 h2 = __floats2half2_rn(ea.x, ea.y);
    erec[pos] = make_uint2((unsigned)srcp[eid], *(unsigned*)&h2);
  }
}

// ---- gather: per (type,node) walk sorted run ONCE, both layers' convs in
// registers. Zero LDS/atomics in the loop. Fuses softmax, skip, minmax.
__global__ __launch_bounds__(256) void k_gather(
    const int* __restrict__ gs2, const int* __restrict__ glen,
    const uint2* __restrict__ erec,
    const float* __restrict__ xall, const float* __restrict__ par,
    const float* __restrict__ Wl, const float* __restrict__ bl,
    float* __restrict__ g, unsigned* __restrict__ mm){
  const int t = blockIdx.y;
  const int dt = c_dtype[t], st = c_stype[t];
  const int N = c_N[dt];
  if (blockIdx.x*256 >= N) return;
  __shared__ float sA[160], sB[160];
  __shared__ float wlb[192];
  __shared__ float smin[4], smax[4];
  const int tid = threadIdx.x;
  if (tid < 160){ sA[tid] = par[(size_t)t*160 + tid]; sB[tid] = par[(size_t)(15+t)*160 + tid]; }
  if (tid < 192) wlb[tid] = (tid<128)? Wl[tid] : bl[tid-128];
  __syncthreads();
  const int n = blockIdx.x*256 + tid;
  const bool valid = n < N;
  float lmin = 3.4e38f, lmax = -3.4e38f;
  if (valid){
    const float4* xdp = (const float4*)(xall + (size_t)(c_xoff[dt]+n)*8);
    float4 b0v = xdp[0], b1v = xdp[1];
    float xd[8] = {b0v.x,b0v.y,b0v.z,b0v.w,b1v.x,b1v.y,b1v.z,b1v.w};
    float r2a[8], r2b[8];
    #pragma unroll
    for (int fs=0; fs<8; fs++){
      float a = sA[72+fs], bb = sB[72+fs];
      #pragma unroll
      for (int fd=0; fd<8; fd++){ a = fmaf(xd[fd], sA[fd*8+fs], a); bb = fmaf(xd[fd], sB[fd*8+fs], bb); }
      r2a[fs]=a; r2b[fs]=bb;
    }
    float t0a=sA[137], t1a=sA[138], tba=sA[139], u0a=sA[136];
    float t0b=sB[137], t1b=sB[138], tbb=sB[139], u0b=sB[136];
    #pragma unroll
    for (int f=0;f<8;f++){
      t0a = fmaf(xd[f], sA[80+f], t0a);  t0b = fmaf(xd[f], sB[80+f], t0b);
      t1a = fmaf(xd[f], sA[88+f], t1a);  t1b = fmaf(xd[f], sB[88+f], t1b);
      tba = fmaf(xd[f], sA[96+f], tba);  tbb = fmaf(xd[f], sB[96+f], tbb);
      u0a = fmaf(xd[f], sA[64+f], u0a);  u0b = fmaf(xd[f], sB[64+f], u0b);
    }
    const float accda = u0a + tba, accdb = u0b + tbb;
    const int o = c_toff2[t];
    const int js = gs2[o+n], je = js + glen[o+n];
    float denA=0.f, n0A=0.f, n1A=0.f;
    float denB=0.f, n0B=0.f, n1B=0.f;
    for (int j=js; j<je; j++){
      const uint2 rec = erec[j];
      const int src = (int)rec.x;
      const __half2 h2 = *(const __half2*)&rec.y;
      const float eax = __low2float(h2), eay = __high2float(h2);
      const float4* xsp = (const float4*)(xall + (size_t)(c_xoff[st]+src)*8);
      float4 a0v = xsp[0], a1v = xsp[1];
      float xs[8] = {a0v.x,a0v.y,a0v.z,a0v.w,a1v.x,a1v.y,a1v.z,a1v.w};
      float accA = accda, accB = accdb;
      float v0A = fmaf(eax, sA[140], fmaf(eay, sA[142], sA[144]+sA[146]));
      float v1A = fmaf(eax, sA[141], fmaf(eay, sA[143], sA[145]+sA[147]));
      float v0B = fmaf(eax, sB[140], fmaf(eay, sB[142], sB[144]+sB[146]));
      float v1B = fmaf(eax, sB[141], fmaf(eay, sB[143], sB[145]+sB[147]));
      #pragma unroll
      for (int f=0;f<8;f++){
        accA = fmaf(xs[f], r2a[f], accA);   accB = fmaf(xs[f], r2b[f], accB);
        v0A  = fmaf(xs[f], sA[104+f], v0A); v0B  = fmaf(xs[f], sB[104+f], v0B);
        v1A  = fmaf(xs[f], sA[112+f], v1A); v1B  = fmaf(xs[f], sB[112+f], v1B);
      }
      accA = fmaf(eax, t0a, fmaf(eay, t1a, accA));
      accB = fmaf(eax, t0b, fmaf(eay, t1b, accB));
      const float peA = __expf(accA * 0.08838834764831845f);
      const float peB = __expf(accB * 0.08838834764831845f);
      denA += peA; n0A = fmaf(peA, v0A, n0A); n1A = fmaf(peA, v1A, n1A);
      denB += peB; n0B = fmaf(peB, v0B, n0B); n1B = fmaf(peB, v1B, n1B);
    }
    const float invA = 1.0f/(denA + 1e-16f);
    const float invB = 1.0f/(denB + 1e-16f);
    float s0a = fmaf(n0A, invA, sA[148]), s1a = fmaf(n1A, invA, sA[149]);
    float s0b = fmaf(n0B, invB, sB[148]), s1b = fmaf(n1B, invB, sB[149]);
    #pragma unroll
    for (int f=0;f<8;f++){
      s0a = fmaf(xd[f], sA[120+f], s0a); s1a = fmaf(xd[f], sA[128+f], s1a);
      s0b = fmaf(xd[f], sB[120+f], s0b); s1b = fmaf(xd[f], sB[128+f], s1b);
    }
    const int baseA = c_aggoff[dt] + (0*c_cnt[dt] + c_slot[t])*N + n;
    const int baseB = c_aggoff[dt] + (1*c_cnt[dt] + c_slot[t])*N + n;
    ((float2*)g)[baseA] = make_float2(s0a, s1a);
    ((float2*)g)[baseB] = make_float2(s0b, s1b);
    #pragma unroll
    for (int h=0;h<64;h++){
      float za = fmaf(s0a, wlb[h], fmaf(s1a, wlb[64+h], wlb[128+h]));
      float zb = fmaf(s0b, wlb[h], fmaf(s1b, wlb[64+h], wlb[128+h]));
      lmin = fminf(lmin, fminf(za,zb)); lmax = fmaxf(lmax, fmaxf(za,zb));
    }
  }
  #pragma unroll
  for (int m=32;m>=1;m>>=1){
    lmin = fminf(lmin, __shfl_xor(lmin,m));
    lmax = fmaxf(lmax, __shfl_xor(lmax,m));
  }
  const int wv = tid>>6;
  if ((tid&63)==0){ smin[wv]=lmin; smax[wv]=lmax; }
  __syncthreads();
  if (tid==0){
    float mn = fminf(fminf(smin[0],smin[1]), fminf(smin[2],smin[3]));
    float mx = fmaxf(fmaxf(smax[0],smax[1]), fmaxf(smax[2],smax[3]));
    atomicMin(&mm[0], encf(mn));
    atomicMax(&mm[1], encf(mx));
  }
}

// ---- final: wave handles 32 rows (2-row ILP); Wfc column resident in VGPRs ----
__global__ __launch_bounds__(256) void k_final(
    const float* __restrict__ g, const unsigned* __restrict__ mm,
    const float* __restrict__ Wl, const float* __restrict__ bl,
    const float* __restrict__ Wfc, const float* __restrict__ bfc,
    const float* __restrict__ Wl2, const float* __restrict__ bl2,
    float* __restrict__ out){
  const int bid = blockIdx.x;
  int nt, bo;
  if (bid < 188)       { nt=0; bo=0; }
  else if (bid < 2063) { nt=1; bo=188; }
  else if (bid < 3001) { nt=2; bo=2063; }
  else                 { nt=3; bo=3001; }
  const int w = threadIdx.x>>6, lane = threadIdx.x&63;
  const int R = c_aggrows[nt];
  const int r0 = (bid-bo)*128 + w*32;
  if (r0 >= R) return;  // wave-uniform
  const float wl0 = Wl[lane], wl1 = Wl[64+lane], blv = bl[lane];
  const float bfcv = bfc[nt*64+lane];
  const float wl20 = Wl2[lane], wl21 = Wl2[64+lane], bl2v = bl2[lane];
  float wfcr[64];
  const float* W = Wfc + (size_t)nt*4096;
  #pragma unroll
  for (int h=0;h<64;h++) wfcr[h] = W[h*64 + lane];
  const float zmin = decf(mm[0]), zmax = decf(mm[1]);
  const float rmin = 0.1f*eluf(zmin);
  const float rmax = 0.9f + 0.1f*eluf(zmax);
  const float s2 = 2.0f/(rmax - rmin + 1e-5f);
  const int nrows = min(32, R - r0);
  float gx=0.f, gy=0.f;
  if (lane < nrows){
    const float2 gv = ((const float2*)g)[c_aggoff[nt] + r0 + lane];
    gx = gv.x; gy = gv.y;
  }
  const int half = min(16, nrows);
  for (int r=0; r<half; r++){
    const int rb = r+16;
    const bool hasB = rb < nrows;
    const float g0a=RL(gx,r),  g1a=RL(gy,r);
    const float g0b=RL(gx,rb), g1b=RL(gy,rb);
    const float za = fmaf(g0a, wl0, fmaf(g1a, wl1, blv));
    const float zb = fmaf(g0b, wl0, fmaf(g1b, wl1, blv));
    const float na = fmaf(eluf(za) - rmin, s2, -1.0f);
    const float nb = fmaf(eluf(zb) - rmin, s2, -1.0f);
    float acca = bfcv, accb = bfcv;
    #pragma unroll
    for (int h=0;h<64;h++){
      acca = fmaf(RL(na,h), wfcr[h], acca);
      accb = fmaf(RL(nb,h), wfcr[h], accb);
    }
    float ba = eluf(acca), bb = eluf(accb);
    float sa = ba, sb = bb;
    sa += __shfl_xor(sa,16); sb += __shfl_xor(sb,16);
    sa += __shfl_xor(sa,8);  sb += __shfl_xor(sb,8);
    sa += __shfl_xor(sa,4);  sb += __shfl_xor(sb,4);
    sa += __shfl_xor(sa,2);  sb += __shfl_xor(sb,2);
    sa += __shfl_xor(sa,1);  sb += __shfl_xor(sb,1);
    const float h0a = RL(sa,0), h1a = RL(sa,32);
    const float h0b = RL(sb,0), h1b = RL(sb,32);
    const float fa = eluf(fmaf(h0a, wl20, fmaf(h1a, wl21, bl2v)));
    const float fb = eluf(fmaf(h0b, wl20, fmaf(h1b, wl21, bl2v)));
    const size_t orowA = (size_t)c_outoff[nt] + r0 + r;
    out[orowA*64 + lane] = fa;
    out[(orowA + (size_t)R)*64 + lane] = fa;
    if (hasB){
      const size_t orowB = (size_t)c_outoff[nt] + r0 + rb;
      out[orowB*64 + lane] = fb;
      out[(orowB + (size_t)R)*64 + lane] = fb;
    }
  }
}

extern "C" void kernel_launch(void* const* d_in, const int* in_sizes, int n_in,
                              void* d_out, int out_size, void* d_ws, size_t ws_size,
                              hipStream_t stream) {
  const float* xSB = (const float*)d_in[0];
  const float* cSB = (const float*)d_in[1];
  const float* xPQ = (const float*)d_in[2];
  const float* cPQ = (const float*)d_in[3];
  const float* xPV = (const float*)d_in[4];
  const float* cPV = (const float*)d_in[5];
  const float* xNB = (const float*)d_in[6];
  const float* cNB = (const float*)d_in[7];
  const int*   eidx = (const int*)d_in[8];
  const float* eattr= (const float*)d_in[9];
  const float* Wq = (const float*)d_in[10];
  const float* bq = (const float*)d_in[11];
  const float* Wk = (const float*)d_in[12];
  const float* bk = (const float*)d_in[13];
  const float* Wv = (const float*)d_in[14];
  const float* bv = (const float*)d_in[15];
  const float* We = (const float*)d_in[16];
  const float* be = (const float*)d_in[17];
  const float* Ws = (const float*)d_in[18];
  const float* bs = (const float*)d_in[19];
  const float* Wl = (const float*)d_in[20];
  const float* bl = (const float*)d_in[21];
  const float* Wfc= (const float*)d_in[22];
  const float* bfc= (const float*)d_in[23];
  const float* Wl2= (const float*)d_in[24];
  const float* bl2= (const float*)d_in[25];

  float* ws    = (float*)d_ws;
  float* xall  = ws + 0;                    // 488000 f
  float* par   = ws + 488000;               // 4800 f
  int* gs2     = (int*)(ws + 492800);       // 240015 i
  int* glen    = (int*)(ws + 732815);       // 240015 i
  int* gcnt    = (int*)(ws + 972830);       // 240 i
  int* gofs    = (int*)(ws + 973070);       // 240 i
  int* gcur    = (int*)(ws + 973310);       // 240 i
  unsigned* mm = (unsigned*)(ws + 973550);  // 2
  unsigned* ebuf = (unsigned*)(ws + 973552);// 2250000 u32 (stage-1 buckets)
  float* g     = ws + 973552;               // 960000 f (aliases ebuf; ebuf dead after k_tsort)
  uint2* erec  = (uint2*)(ws + 3223552);    // 2250000 uint2 (even offset -> 8B aligned)
  // end: 7723552 floats ~= 30.9 MB

  hipMemsetAsync(gcnt, 0, 240*sizeof(int), stream);
  hipMemsetAsync(mm,   0xFF, 4, stream);
  hipMemsetAsync(mm+1, 0x00, 4, stream);

  k_build_x<<<(61000+255)/256, 256, 0, stream>>>(xSB,cSB,xPQ,cPQ,xPV,cPV,xNB,cNB, xall);
  k_params<<<30, 128, 0, stream>>>(Wq,bq,Wk,bk,Wv,bv,We,be,Ws,bs, par);
  dim3 gb(8, 15);
  k_count<<<gb, 1024, 0, stream>>>(eidx, gcnt);
  k_scan<<<1, 64, 0, stream>>>(gcnt, gofs, gcur);
  k_scatter<<<gb, 1024, 0, stream>>>(eidx, gcur, ebuf);
  k_tsort<<<240, 1024, 0, stream>>>(ebuf, eidx, eattr, gofs, gcnt, erec, gs2, glen);
  dim3 gg((30000+255)/256, 15);
  k_gather<<<gg, 256, 0, stream>>>(gs2, glen, erec, xall, par, Wl, bl, g, mm);
  k_final<<<3751, 256, 0, stream>>>(g, mm, Wl, bl, Wfc, bfc, Wl2, bl2, (float*)d_out);
}